// Round 7
// baseline (305.213 us; speedup 1.0000x reference)
//
#include <hip/hip_runtime.h>
#include <math.h>

#define BB   16
#define NN   2048
#define DIN  512
#define DKK  10
#define NHD  2
#define DH   5
#define HID  20
#define DOUT 512
#define BH   32          // BB*NHD
#define KC   256         // attention k-chunk
#define NKC  8           // NN/KC
#define PC   64          // proj dim-chunk staged in LDS

// ws layout (floats):
//   qkv  : [3][BH][NN][8]   (q pre-scaled by 1/sqrt(5); rows padded 5->8)
//   part : [NKC][BH][NN][8] (acc[0..4], denom at [5])
//   Wpack: [512][32]        (Wq|Wk|Wv rows packed+padded, 128B-aligned rows)
//   h1   : [B*N][20]        overlays qkv (dead after attn) -> no ws growth
#define QKV_ELEMS  ((size_t)3*BH*NN*8)
#define PART_ELEMS ((size_t)NKC*BH*NN*8)

// ---------------------------------------------------------------- kernel 0
// Pack Wq|Wk|Wv into [512][32] rows (cols 0-9 q, 10-19 k, 20-29 v, 30-31 zero)
__global__ __launch_bounds__(256) void pack_w_kernel(
    const float* __restrict__ Wq, const float* __restrict__ Wk,
    const float* __restrict__ Wv, float* __restrict__ Wpack)
{
    const int idx = blockIdx.x*256 + threadIdx.x;   // 0..16383
    const int j = idx >> 5, c = idx & 31;
    float v = 0.f;
    if (c < 10)      v = Wq[j*DKK + c];
    else if (c < 20) v = Wk[j*DKK + (c-10)];
    else if (c < 30) v = Wv[j*DKK + (c-20)];
    Wpack[idx] = v;
}

// ---------------------------------------------------------------- kernel 1
// Block 256 = 4 waves. lane = token (64/block), wave = out-group of 8 cols.
// x staged TRANSPOSED in LDS (xs[dim][tok+pad]: stride-1 b32 reads, 2-way
// free); W staged in LDS too (wave-uniform float4 broadcasts, conflict-free).
// v6's W came via SMEM s_loads whose OOO completion forced lgkmcnt(0) full
// drains每batch; all-LDS -> compiler emits counted lgkmcnt pipelining.
__global__ __launch_bounds__(256) void proj_kernel(
    const float* __restrict__ x, const float* __restrict__ Wpack,
    const float* __restrict__ bq, const float* __restrict__ bk,
    const float* __restrict__ bv, float* __restrict__ qkv)
{
    __shared__ float xs[PC][65];        // 16.6 KB
    __shared__ float wls[PC*32];        // 8 KB
    const int t    = threadIdx.x;
    const int lane = t & 63;
    const int grp  = t >> 6;            // 0..3
    const int tok0 = blockIdx.x*64;

    float acc[8];
    #pragma unroll
    for (int i=0;i<8;i++) acc[i]=0.f;

    for (int ch=0; ch<DIN/PC; ++ch){
        __syncthreads();
        // stage 64 tok x 64 dims (1024 float4, 4/thread), transposed into LDS
        #pragma unroll
        for (int p=0;p<4;p++){
            const int f  = t + p*256;
            const int tt = f >> 4;              // token 0..63
            const int dd = (f & 15) * 4;        // dim 0,4,..60
            const float4 v = *(const float4*)(x + (size_t)(tok0+tt)*DIN + ch*PC + dd);
            xs[dd+0][tt]=v.x; xs[dd+1][tt]=v.y; xs[dd+2][tt]=v.z; xs[dd+3][tt]=v.w;
        }
        // stage W chunk 64 rows x 32 cols (512 float4, 2/thread)
        #pragma unroll
        for (int p=0;p<2;p++){
            const int f = t + p*256;
            ((float4*)wls)[f] = ((const float4*)(Wpack + (size_t)ch*PC*32))[f];
        }
        __syncthreads();

        for (int k=0;k<PC;k+=4){
            float w[4][8]; float xv[4];
            #pragma unroll
            for (int i=0;i<4;i++){
                xv[i] = xs[k+i][lane];
                const float4* wrow = (const float4*)(wls + (size_t)(k+i)*32 + grp*8);
                const float4 wa = wrow[0], wb = wrow[1];   // uniform -> broadcast
                w[i][0]=wa.x; w[i][1]=wa.y; w[i][2]=wa.z; w[i][3]=wa.w;
                w[i][4]=wb.x; w[i][5]=wb.y; w[i][6]=wb.z; w[i][7]=wb.w;
            }
            #pragma unroll
            for (int i=0;i<4;i++){
                #pragma unroll
                for (int o=0;o<8;o++) acc[o] = fmaf(xv[i], w[i][o], acc[o]);
            }
        }
    }

    const float qs = 0.44721359549995793f;      // 1/sqrt(5) folded into Q
    const int tok = tok0 + lane;
    const int b   = tok >> 11;
    const int n   = tok & (NN-1);
    #pragma unroll
    for (int i=0;i<8;i++){
        const int c = grp*8 + i;
        if (c >= 30) continue;
        const int mat = c / 10;
        const int d10 = c - mat*10;
        const int h   = d10 / 5;
        const int dd  = d10 - h*5;
        float v = acc[i] + ((mat==0) ? bq[d10] : (mat==1) ? bk[d10] : bv[d10]);
        if (mat==0) v *= qs;
        qkv[(size_t)mat*BH*NN*8 + (((size_t)(b*NHD+h))*NN + n)*8 + dd] = v;
    }
}

// ---------------------------------------------------------------- kernel 2
// 1-wave blocks; 4 q-rows per lane (wave covers 256 q rows), k-chunk 256.
// Per 4-k batch: 16 VMEM loads then ~480 VALU cycles (4q ILP hides latency
// even at ~1 wave/SIMD). Opaque zero forces vector loads (not SMEM s_loads,
// whose OOO completion would force full lgkmcnt drains per batch).
// scores = sin(q.k/sqrt5) in [-1,1] -> exp needs no max pass.
__global__ __launch_bounds__(64) void attn_kernel(
    const float* __restrict__ qkv, float* __restrict__ part)
{
    const int qt = blockIdx.x;          // 0..7 (256 q rows each)
    const int kc = blockIdx.y;          // 0..7
    const int bh = blockIdx.z;
    if (kc > qt) return;                // causal early-out
    const int lane = threadIdx.x;
    const int k0 = kc*KC;
    const int zr = (int)(blockDim.y >> 16);   // provably-opaque 0

    int q[4]; const float* qr[4];
    float4 qv[4]; float q4[4];
    #pragma unroll
    for (int i=0;i<4;i++){
        q[i]  = qt*256 + i*64 + lane;
        qr[i] = qkv + ((size_t)bh*NN + q[i])*8;
        qv[i] = *(const float4*)qr[i];
        q4[i] = qr[i][4];
    }

    const float* kb = qkv + (size_t)BH*NN*8 + (size_t)bh*NN*8;
    const float* vb = kb + (size_t)BH*NN*8;

    float den[4] = {0,0,0,0};
    float a0[4]={0,0,0,0}, a1[4]={0,0,0,0}, a2[4]={0,0,0,0},
          a3[4]={0,0,0,0}, a4[4]={0,0,0,0};

    for (int kk=0; kk<KC; kk+=4){
        float4 K4[4], V4[4]; float K1[4], V1[4];
        #pragma unroll
        for (int i=0;i<4;i++){
            const float* kr = kb + (size_t)(k0+kk+i+zr)*8;
            const float* vr = vb + (size_t)(k0+kk+i+zr)*8;
            K4[i]=*(const float4*)kr; K1[i]=kr[4];
            V4[i]=*(const float4*)vr; V1[i]=vr[4];
        }
        #pragma unroll
        for (int i=0;i<4;i++){
            const int kg = k0+kk+i;
            #pragma unroll
            for (int j=0;j<4;j++){
                float s = qv[j].x*K4[i].x + qv[j].y*K4[i].y + qv[j].z*K4[i].z
                        + qv[j].w*K4[i].w + q4[j]*K1[i];
                float e = __expf(__sinf(s));
                e = (kg <= q[j]) ? e : 0.f;
                den[j] += e;
                a0[j] = fmaf(e, V4[i].x, a0[j]);
                a1[j] = fmaf(e, V4[i].y, a1[j]);
                a2[j] = fmaf(e, V4[i].z, a2[j]);
                a3[j] = fmaf(e, V4[i].w, a3[j]);
                a4[j] = fmaf(e, V1[i],   a4[j]);
            }
        }
    }
    #pragma unroll
    for (int j=0;j<4;j++){
        float* pr = part + (((size_t)kc*BH + bh)*NN + q[j])*8;
        *(float4*)pr = make_float4(a0[j],a1[j],a2[j],a3[j]);
        pr[4] = a4[j];
        pr[5] = den[j];
    }
}

// ---------------------------------------------------------------- kernel 3a
// One TOKEN PER LANE: part-reduce + Wm1 + leaky_relu, write h1[tok][20].
__global__ __launch_bounds__(256) void h1_kernel(
    const float* __restrict__ part,
    const float* __restrict__ Wm1, const float* __restrict__ bm1,
    float* __restrict__ h1buf)
{
    const int tok = blockIdx.x*256 + threadIdx.x;   // 0..32767
    const int b   = tok >> 11;
    const int n   = tok & (NN-1);
    const int nc  = (n >> 8) + 1;                   // valid causal k-chunks

    float vals[DKK];
    #pragma unroll
    for (int h=0;h<NHD;h++){
        const int bh = b*NHD + h;
        float s0=0,s1=0,s2=0,s3=0,s4=0,sd=0;
        for (int c=0;c<nc;c++){
            const float* pr = part + (((size_t)c*BH + bh)*NN + n)*8;
            const float4 p0 = *(const float4*)pr;
            const float4 p1 = *(const float4*)(pr+4);
            s0+=p0.x; s1+=p0.y; s2+=p0.z; s3+=p0.w; s4+=p1.x; sd+=p1.y;
        }
        const float inv = 1.0f / sd;
        vals[h*DH+0]=s0*inv; vals[h*DH+1]=s1*inv; vals[h*DH+2]=s2*inv;
        vals[h*DH+3]=s3*inv; vals[h*DH+4]=s4*inv;
    }

    float h1[HID];
    #pragma unroll
    for (int jo=0;jo<HID;jo++){
        float t = bm1[jo];
        #pragma unroll
        for (int d=0;d<DKK;d++) t = fmaf(vals[d], Wm1[d*HID+jo], t);
        h1[jo] = (t > 0.f) ? t : 0.01f*t;
    }
    float* hr = h1buf + (size_t)tok*HID;            // 80B rows, 16B-aligned
    #pragma unroll
    for (int j5=0;j5<5;j5++)
        *(float4*)(hr + j5*4) = make_float4(h1[j5*4+0],h1[j5*4+1],h1[j5*4+2],h1[j5*4+3]);
}

// ---------------------------------------------------------------- kernel 3b
// One wave = half an output row (256 cols, 4/lane) for 8 tokens; Wm2 slice
// in registers; per token: 20 uniform h1 loads + 80 FMA + dwordx4 store.
__global__ __launch_bounds__(256) void out_kernel(
    const float* __restrict__ h1buf,
    const float* __restrict__ Wm2, const float* __restrict__ bm2,
    float* __restrict__ out)
{
    const int wave = threadIdx.x >> 6;
    const int lane = threadIdx.x & 63;
    const int unit = blockIdx.x*4 + wave;   // 0..8191
    const int hc   = unit & 1;
    const int tg   = unit >> 1;
    const int o0   = hc*256 + lane*4;

    float4 w2[HID];
    #pragma unroll
    for (int j=0;j<HID;j++) w2[j] = *(const float4*)(Wm2 + j*DOUT + o0);
    const float4 b2 = *(const float4*)(bm2 + o0);

    for (int ti=0; ti<8; ++ti){
        const int tok = tg*8 + ti;
        const float* hr = h1buf + (size_t)tok*HID;  // wave-uniform
        float4 acc = b2;
        #pragma unroll
        for (int j5=0;j5<5;j5++){
            const float4 hv = *(const float4*)(hr + j5*4);
            const float h0=hv.x, h1v=hv.y, h2=hv.z, h3=hv.w;
            acc.x = fmaf(h0, w2[j5*4+0].x, acc.x);
            acc.y = fmaf(h0, w2[j5*4+0].y, acc.y);
            acc.z = fmaf(h0, w2[j5*4+0].z, acc.z);
            acc.w = fmaf(h0, w2[j5*4+0].w, acc.w);
            acc.x = fmaf(h1v, w2[j5*4+1].x, acc.x);
            acc.y = fmaf(h1v, w2[j5*4+1].y, acc.y);
            acc.z = fmaf(h1v, w2[j5*4+1].z, acc.z);
            acc.w = fmaf(h1v, w2[j5*4+1].w, acc.w);
            acc.x = fmaf(h2, w2[j5*4+2].x, acc.x);
            acc.y = fmaf(h2, w2[j5*4+2].y, acc.y);
            acc.z = fmaf(h2, w2[j5*4+2].z, acc.z);
            acc.w = fmaf(h2, w2[j5*4+2].w, acc.w);
            acc.x = fmaf(h3, w2[j5*4+3].x, acc.x);
            acc.y = fmaf(h3, w2[j5*4+3].y, acc.y);
            acc.z = fmaf(h3, w2[j5*4+3].z, acc.z);
            acc.w = fmaf(h3, w2[j5*4+3].w, acc.w);
        }
        *(float4*)(out + (size_t)tok*DOUT + o0) = acc;
    }
}

// ---------------------------------------------------------------- launch
extern "C" void kernel_launch(void* const* d_in, const int* in_sizes, int n_in,
                              void* d_out, int out_size, void* d_ws, size_t ws_size,
                              hipStream_t stream) {
    const float* x   = (const float*)d_in[0];
    const float* Wq  = (const float*)d_in[1];
    const float* bq  = (const float*)d_in[2];
    const float* Wk  = (const float*)d_in[3];
    const float* bk  = (const float*)d_in[4];
    const float* Wv  = (const float*)d_in[5];
    const float* bv  = (const float*)d_in[6];
    const float* Wm1 = (const float*)d_in[7];
    const float* bm1 = (const float*)d_in[8];
    const float* Wm2 = (const float*)d_in[9];
    const float* bm2 = (const float*)d_in[10];
    float* out = (float*)d_out;

    float* qkv   = (float*)d_ws;
    float* part  = qkv + QKV_ELEMS;
    float* Wpack = part + PART_ELEMS;
    float* h1buf = qkv;   // overlays qkv: dead after attn_kernel (stream-ordered)

    pack_w_kernel<<<dim3(64), dim3(256), 0, stream>>>(Wq, Wk, Wv, Wpack);
    proj_kernel<<<dim3(512), dim3(256), 0, stream>>>(x, Wpack, bq, bk, bv, qkv);
    attn_kernel<<<dim3(8, 8, BH), dim3(64), 0, stream>>>(qkv, part);
    h1_kernel<<<dim3(128), dim3(256), 0, stream>>>(part, Wm1, bm1, h1buf);
    out_kernel<<<dim3(2048), dim3(256), 0, stream>>>(h1buf, Wm2, bm2, out);
}

// Round 9
// 252.877 us; speedup vs baseline: 1.2070x; 1.2070x over previous
//
#include <hip/hip_runtime.h>
#include <math.h>

#define BB   16
#define NN   2048
#define DIN  512
#define DKK  10
#define NHD  2
#define DH   5
#define HID  20
#define DOUT 512
#define BH   32          // BB*NHD
#define KC   256         // attention k-chunk
#define NKC  8           // NN/KC

typedef __attribute__((ext_vector_type(8))) short bf16x8;
typedef __attribute__((ext_vector_type(4))) float f32x4;

// RNE float->bf16 bits (3 VALU ops, no lib dependency)
__device__ inline unsigned short f2bf(float f){
    union { float f; unsigned int u; } v; v.f = f;
    return (unsigned short)((v.u + 0x7FFFu + ((v.u >> 16) & 1u)) >> 16);
}

// ws layout (floats):
//   qkv : [3][BH][NN][8]   (q pre-scaled by 1/sqrt(5); rows padded 5->8)
//   part: [NKC][BH][NN][8] (acc[0..4], denom at [5])
//   Wbf : 16384 ushort     (B-fragment-ordered bf16 Wq|Wk|Wv, 32 KB)
//   h1  : [B*N][20]        overlays qkv (dead after attn)
#define QKV_ELEMS  ((size_t)3*BH*NN*8)
#define PART_ELEMS ((size_t)NKC*BH*NN*8)

// ---------------------------------------------------------------- kernel 0
// Pack W into MFMA B-fragment order, bf16:
// idx = ((kt*2+t)*64 + l)*8 + i  ->  k = kt*32+(l>>4)*8+i, c = t*16+(l&15)
__global__ __launch_bounds__(256) void pack_wbf_kernel(
    const float* __restrict__ Wq, const float* __restrict__ Wk,
    const float* __restrict__ Wv, unsigned short* __restrict__ Wbf)
{
    const int idx = blockIdx.x*256 + threadIdx.x;   // 0..16383
    const int i  = idx & 7;
    const int l  = (idx >> 3) & 63;
    const int t  = (idx >> 9) & 1;
    const int kt = idx >> 10;                       // 0..15
    const int k  = kt*32 + (l >> 4)*8 + i;
    const int c  = t*16 + (l & 15);
    float v = 0.f;
    if (c < 10)      v = Wq[k*DKK + c];
    else if (c < 20) v = Wk[k*DKK + (c-10)];
    else if (c < 30) v = Wv[k*DKK + (c-20)];
    Wbf[idx] = f2bf(v);
}

// ---------------------------------------------------------------- kernel 1
// MFMA bf16 projection, no LDS, no barriers. Wave = 16 tokens x 32 cols.
// A: direct global x (8 consec fp32/lane -> bf16). B: prepacked Wbf
// (one coalesced 16B load/lane, L1-hot). A/B filled with the SAME
// (group,slot)->k map -> layout-permutation-immune. C/D: col=lane&15,
// row=(lane>>4)*4+reg (m89-verified).
__global__ __launch_bounds__(256) void proj_kernel(
    const float* __restrict__ x, const unsigned short* __restrict__ Wbf,
    const float* __restrict__ bq, const float* __restrict__ bk,
    const float* __restrict__ bv, float* __restrict__ qkv)
{
    const int t    = threadIdx.x;
    const int w    = t >> 6;
    const int l    = t & 63;
    const int tok0 = blockIdx.x*64 + w*16;
    const int row  = l & 15;
    const int g    = l >> 4;
    const float* xr = x + (size_t)(tok0 + row)*DIN + g*8;

    f32x4 acc0 = {0.f,0.f,0.f,0.f};
    f32x4 acc1 = {0.f,0.f,0.f,0.f};

    #pragma unroll 4
    for (int kt = 0; kt < 16; ++kt){
        const float4 xa = *(const float4*)(xr + kt*32);
        const float4 xb = *(const float4*)(xr + kt*32 + 4);
        bf16x8 a;
        a[0]=(short)f2bf(xa.x); a[1]=(short)f2bf(xa.y);
        a[2]=(short)f2bf(xa.z); a[3]=(short)f2bf(xa.w);
        a[4]=(short)f2bf(xb.x); a[5]=(short)f2bf(xb.y);
        a[6]=(short)f2bf(xb.z); a[7]=(short)f2bf(xb.w);
        const bf16x8 b0 = *(const bf16x8*)(Wbf + ((size_t)(kt*2+0)*64 + l)*8);
        const bf16x8 b1 = *(const bf16x8*)(Wbf + ((size_t)(kt*2+1)*64 + l)*8);
        acc0 = __builtin_amdgcn_mfma_f32_16x16x32_bf16(a, b0, acc0, 0, 0, 0);
        acc1 = __builtin_amdgcn_mfma_f32_16x16x32_bf16(a, b1, acc1, 0, 0, 0);
    }

    // epilogue: lane holds cols c0=l&15 / c1=16+(l&15), rows (l>>4)*4+reg
    const float qs = 0.44721359549995793f;      // 1/sqrt(5) folded into Q
    const int c0 = l & 15;
    const int c1 = 16 + c0;
    const int mat0 = (c0 >= 10);                // 0:q, 1:k
    const int d0i  = c0 - mat0*10;
    const int h0   = d0i / 5, dd0 = d0i - h0*5;
    const float bias0 = mat0 ? bk[d0i] : bq[d0i];
    const float scl0  = mat0 ? 1.f : qs;
    const bool  v1ok = (c1 < 30);
    const int mat1 = (c1 < 20) ? 1 : 2;         // 1:k, 2:v
    const int d1i  = (c1 < 20) ? (c1-10) : (c1-20);
    const int h1   = d1i / 5, dd1 = d1i - h1*5;
    const float bias1 = v1ok ? ((c1 < 20) ? bk[d1i] : bv[d1i]) : 0.f;

    #pragma unroll
    for (int r = 0; r < 4; ++r){
        const int token = tok0 + g*4 + r;
        const int b = token >> 11;
        const int n = token & (NN-1);
        const float v0 = (acc0[r] + bias0) * scl0;
        qkv[(size_t)mat0*BH*NN*8 + (((size_t)(b*NHD + h0))*NN + n)*8 + dd0] = v0;
        if (v1ok){
            const float v1 = acc1[r] + bias1;
            qkv[(size_t)mat1*BH*NN*8 + (((size_t)(b*NHD + h1))*NN + n)*8 + dd1] = v1;
        }
    }
}

// ---------------------------------------------------------------- kernel 2
// R6's winning geometry (4-wave blocks, 2 q-rows/lane, 2304 active waves)
// + register ping-pong double-buffer: load batch i+4 while computing batch i
// (2-batch unroll, no reg copies). Opaque zr keeps K/V loads as VMEM
// (countable vmcnt) instead of OOO SMEM s_loads.
// scores = sin(q.k/sqrt5) in [-1,1] -> exp needs no max pass.
__global__ __launch_bounds__(256) void attn_kernel(
    const float* __restrict__ qkv, float* __restrict__ part)
{
    const int qt  = blockIdx.x;         // 0..3 (512 q rows)
    const int kc  = blockIdx.y;         // 0..7
    const int bh  = blockIdx.z;
    const int k0  = kc*KC;
    const int qb0 = qt*512;
    if (k0 >= qb0 + 512) return;        // block causal early-out

    const int w    = threadIdx.x >> 6;
    const int lane = threadIdx.x & 63;
    const int qw0  = qb0 + w*128;       // wave: q in [qw0, qw0+128)
    if (k0 >= qw0 + 128) return;        // wave-uniform early-out
    const int zr = (int)(blockDim.y >> 16);   // provably-opaque 0

    const int q0 = qw0 + lane;
    const int q1 = qw0 + 64 + lane;
    const float* qr0 = qkv + ((size_t)bh*NN + q0)*8;
    const float* qr1 = qkv + ((size_t)bh*NN + q1)*8;
    const float4 qv0 = *(const float4*)qr0; const float q40 = qr0[4];
    const float4 qv1 = *(const float4*)qr1; const float q41 = qr1[4];

    const float* kb = qkv + (size_t)BH*NN*8 + (size_t)bh*NN*8;
    const float* vb = kb + (size_t)BH*NN*8;
    const int kend = min(KC, qw0 + 128 - k0);   // uniform, multiple of 128

    float d0=0,a00=0,a01=0,a02=0,a03=0,a04=0;
    float d1=0,a10=0,a11=0,a12=0,a13=0,a14=0;

    float4 KA[4], VA[4], KB4[4], VB4[4];
    float  K1A[4], V1A[4], K1B[4], V1B[4];

    #define LOADB(K4,K1,V4,V1,BASE) {                              \
        _Pragma("unroll")                                          \
        for (int i=0;i<4;i++){                                     \
            const float* kr = kb + (size_t)((BASE)+i+zr)*8;        \
            const float* vr = vb + (size_t)((BASE)+i+zr)*8;        \
            K4[i]=*(const float4*)kr; K1[i]=kr[4];                 \
            V4[i]=*(const float4*)vr; V1[i]=vr[4];                 \
        } }

    #define COMP(K4,K1,V4,V1,BASE) {                               \
        _Pragma("unroll")                                          \
        for (int i=0;i<4;i++){                                     \
            const int kg = (BASE)+i;                               \
            float s0 = qv0.x*K4[i].x + qv0.y*K4[i].y + qv0.z*K4[i].z \
                     + qv0.w*K4[i].w + q40*K1[i];                  \
            float s1 = qv1.x*K4[i].x + qv1.y*K4[i].y + qv1.z*K4[i].z \
                     + qv1.w*K4[i].w + q41*K1[i];                  \
            float e0 = __expf(__sinf(s0));                         \
            float e1 = __expf(__sinf(s1));                         \
            e0 = (kg <= q0) ? e0 : 0.f;                            \
            e1 = (kg <= q1) ? e1 : 0.f;                            \
            d0 += e0;                                              \
            a00 = fmaf(e0, V4[i].x, a00);                          \
            a01 = fmaf(e0, V4[i].y, a01);                          \
            a02 = fmaf(e0, V4[i].z, a02);                          \
            a03 = fmaf(e0, V4[i].w, a03);                          \
            a04 = fmaf(e0, V1[i],   a04);                          \
            d1 += e1;                                              \
            a10 = fmaf(e1, V4[i].x, a10);                          \
            a11 = fmaf(e1, V4[i].y, a11);                          \
            a12 = fmaf(e1, V4[i].z, a12);                          \
            a13 = fmaf(e1, V4[i].w, a13);                          \
            a14 = fmaf(e1, V1[i],   a14);                          \
        } }

    LOADB(KA,K1A,VA,V1A, k0);
    for (int kk = 0; kk < kend; kk += 8){
        LOADB(KB4,K1B,VB4,V1B, k0+kk+4);
        COMP (KA,K1A,VA,V1A,  k0+kk);
        if (kk + 8 < kend) LOADB(KA,K1A,VA,V1A, k0+kk+8);
        COMP (KB4,K1B,VB4,V1B, k0+kk+4);
    }
    #undef LOADB
    #undef COMP

    float* pr0 = part + (((size_t)kc*BH + bh)*NN + q0)*8;
    *(float4*)pr0 = make_float4(a00,a01,a02,a03);
    pr0[4] = a04; pr0[5] = d0;
    float* pr1 = part + (((size_t)kc*BH + bh)*NN + q1)*8;
    *(float4*)pr1 = make_float4(a10,a11,a12,a13);
    pr1[4] = a14; pr1[5] = d1;
}

// ---------------------------------------------------------------- kernel 3a
// One TOKEN PER LANE: part-reduce + Wm1 + leaky_relu, write h1[tok][20].
__global__ __launch_bounds__(256) void h1_kernel(
    const float* __restrict__ part,
    const float* __restrict__ Wm1, const float* __restrict__ bm1,
    float* __restrict__ h1buf)
{
    const int tok = blockIdx.x*256 + threadIdx.x;   // 0..32767
    const int b   = tok >> 11;
    const int n   = tok & (NN-1);
    const int nc  = (n >> 8) + 1;                   // valid causal k-chunks

    float vals[DKK];
    #pragma unroll
    for (int h=0;h<NHD;h++){
        const int bh = b*NHD + h;
        float s0=0,s1=0,s2=0,s3=0,s4=0,sd=0;
        for (int c=0;c<nc;c++){
            const float* pr = part + (((size_t)c*BH + bh)*NN + n)*8;
            const float4 p0 = *(const float4*)pr;
            const float4 p1 = *(const float4*)(pr+4);
            s0+=p0.x; s1+=p0.y; s2+=p0.z; s3+=p0.w; s4+=p1.x; sd+=p1.y;
        }
        const float inv = 1.0f / sd;
        vals[h*DH+0]=s0*inv; vals[h*DH+1]=s1*inv; vals[h*DH+2]=s2*inv;
        vals[h*DH+3]=s3*inv; vals[h*DH+4]=s4*inv;
    }

    float h1[HID];
    #pragma unroll
    for (int jo=0;jo<HID;jo++){
        float t = bm1[jo];
        #pragma unroll
        for (int d=0;d<DKK;d++) t = fmaf(vals[d], Wm1[d*HID+jo], t);
        h1[jo] = (t > 0.f) ? t : 0.01f*t;
    }
    float* hr = h1buf + (size_t)tok*HID;            // 80B rows, 16B-aligned
    #pragma unroll
    for (int j5=0;j5<5;j5++)
        *(float4*)(hr + j5*4) = make_float4(h1[j5*4+0],h1[j5*4+1],h1[j5*4+2],h1[j5*4+3]);
}

// ---------------------------------------------------------------- kernel 3b
// One wave = half an output row (256 cols, 4/lane) for 8 tokens; Wm2 slice
// in registers; per token: 20 uniform h1 loads + 80 FMA + dwordx4 store.
__global__ __launch_bounds__(256) void out_kernel(
    const float* __restrict__ h1buf,
    const float* __restrict__ Wm2, const float* __restrict__ bm2,
    float* __restrict__ out)
{
    const int wave = threadIdx.x >> 6;
    const int lane = threadIdx.x & 63;
    const int unit = blockIdx.x*4 + wave;   // 0..8191
    const int hc   = unit & 1;
    const int tg   = unit >> 1;
    const int o0   = hc*256 + lane*4;

    float4 w2[HID];
    #pragma unroll
    for (int j=0;j<HID;j++) w2[j] = *(const float4*)(Wm2 + j*DOUT + o0);
    const float4 b2 = *(const float4*)(bm2 + o0);

    for (int ti=0; ti<8; ++ti){
        const int tok = tg*8 + ti;
        const float* hr = h1buf + (size_t)tok*HID;  // wave-uniform
        float4 acc = b2;
        #pragma unroll
        for (int j5=0;j5<5;j5++){
            const float4 hv = *(const float4*)(hr + j5*4);
            const float h0=hv.x, h1v=hv.y, h2=hv.z, h3=hv.w;
            acc.x = fmaf(h0, w2[j5*4+0].x, acc.x);
            acc.y = fmaf(h0, w2[j5*4+0].y, acc.y);
            acc.z = fmaf(h0, w2[j5*4+0].z, acc.z);
            acc.w = fmaf(h0, w2[j5*4+0].w, acc.w);
            acc.x = fmaf(h1v, w2[j5*4+1].x, acc.x);
            acc.y = fmaf(h1v, w2[j5*4+1].y, acc.y);
            acc.z = fmaf(h1v, w2[j5*4+1].z, acc.z);
            acc.w = fmaf(h1v, w2[j5*4+1].w, acc.w);
            acc.x = fmaf(h2, w2[j5*4+2].x, acc.x);
            acc.y = fmaf(h2, w2[j5*4+2].y, acc.y);
            acc.z = fmaf(h2, w2[j5*4+2].z, acc.z);
            acc.w = fmaf(h2, w2[j5*4+2].w, acc.w);
            acc.x = fmaf(h3, w2[j5*4+3].x, acc.x);
            acc.y = fmaf(h3, w2[j5*4+3].y, acc.y);
            acc.z = fmaf(h3, w2[j5*4+3].z, acc.z);
            acc.w = fmaf(h3, w2[j5*4+3].w, acc.w);
        }
        *(float4*)(out + (size_t)tok*DOUT + o0) = acc;
    }
}

// ---------------------------------------------------------------- launch
extern "C" void kernel_launch(void* const* d_in, const int* in_sizes, int n_in,
                              void* d_out, int out_size, void* d_ws, size_t ws_size,
                              hipStream_t stream) {
    const float* x   = (const float*)d_in[0];
    const float* Wq  = (const float*)d_in[1];
    const float* bq  = (const float*)d_in[2];
    const float* Wk  = (const float*)d_in[3];
    const float* bk  = (const float*)d_in[4];
    const float* Wv  = (const float*)d_in[5];
    const float* bv  = (const float*)d_in[6];
    const float* Wm1 = (const float*)d_in[7];
    const float* bm1 = (const float*)d_in[8];
    const float* Wm2 = (const float*)d_in[9];
    const float* bm2 = (const float*)d_in[10];
    float* out = (float*)d_out;

    float* qkv   = (float*)d_ws;
    float* part  = qkv + QKV_ELEMS;
    unsigned short* Wbf = (unsigned short*)(part + PART_ELEMS);
    float* h1buf = qkv;   // overlays qkv: dead after attn_kernel

    pack_wbf_kernel<<<dim3(64), dim3(256), 0, stream>>>(Wq, Wk, Wv, Wbf);
    proj_kernel<<<dim3(512), dim3(256), 0, stream>>>(x, Wbf, bq, bk, bv, qkv);
    attn_kernel<<<dim3(4, NKC, BH), dim3(256), 0, stream>>>(qkv, part);
    h1_kernel<<<dim3(128), dim3(256), 0, stream>>>(part, Wm1, bm1, h1buf);
    out_kernel<<<dim3(2048), dim3(256), 0, stream>>>(h1buf, Wm2, bm2, out);
}